// Round 14
// baseline (707.223 us; speedup 1.0000x reference)
//
#include <hip/hip_runtime.h>
#include <cstdint>
#include <cstddef>

// Problem constants
#define B_   16
#define N_   576
#define D_   768
#define H_   8
#define HD_  96
#define DF_  3072
#define R_   (B_*N_)               // 9216 rows per block-input; 2R = 18432 combined
#define SCALE_F 0.10206207261596575f  // 96^-0.5

typedef __bf16 bf16;
typedef __attribute__((ext_vector_type(8))) __bf16 bf16x8;
typedef __attribute__((ext_vector_type(4))) __bf16 bf16x4;
typedef __attribute__((ext_vector_type(4))) float  f32x4;

__device__ __forceinline__ void gld_lds16(const void* g, void* l) {
  __builtin_amdgcn_global_load_lds((const __attribute__((address_space(1))) void*)g,
                                   (__attribute__((address_space(3))) void*)l,
                                   16, 0, 0);
}
__device__ __forceinline__ void nt_f32(float* p, float v) { __builtin_nontemporal_store(v, p); }
// tanh-form gelu (max dev vs exact erf-gelu ~3e-3; threshold 0.104, current absmax 0.031)
__device__ __forceinline__ float gelu_f(float v) {
  float u = 0.7978845608028654f * v * (1.0f + 0.044715f*v*v);
  float e = __expf(2.0f*u);                  // overflow->inf is fine (th->1)
  float th = 1.0f - 2.0f/(e + 1.0f);
  return 0.5f*v*(1.0f + th);
}

// ---------------- prep kernels ----------------
__global__ void cast_f32_bf16_k(const float* __restrict__ x, bf16* __restrict__ y, int n4) {
  int i = blockIdx.x*256 + threadIdx.x;
  if (i >= n4) return;
  f32x4 v = ((const f32x4*)x)[i];
  union { bf16 h[4]; unsigned long long q; } u;
  u.h[0] = (bf16)v[0]; u.h[1] = (bf16)v[1]; u.h[2] = (bf16)v[2]; u.h[3] = (bf16)v[3];
  ((unsigned long long*)y)[i] = u.q;         // cached: consumed by QKV GEMM
}

// WT[c][r] = (bf16)W[r][c];  rows, cols multiples of 32
__global__ void transpose_cast_k(const float* __restrict__ W, bf16* __restrict__ WT,
                                 int rows, int cols) {
  __shared__ float tile[32][33];
  int cb = blockIdx.x*32, rb = blockIdx.y*32;
  int tx = threadIdx.x, ty = threadIdx.y;   // block (32,8)
  #pragma unroll
  for (int i=0;i<32;i+=8)
    tile[ty+i][tx] = W[(size_t)(rb+ty+i)*cols + cb+tx];
  __syncthreads();
  #pragma unroll
  for (int i=0;i<32;i+=8)
    WT[(size_t)(cb+ty+i)*rows + rb+tx] = (bf16)tile[tx][ty+i];
}

__global__ void concat_bias_k(const float* a, const float* b, const float* c, float* o) {
  int i = blockIdx.x*256 + threadIdx.x;
  if (i < 768) o[i] = a[i];
  else if (i < 1536) o[i] = b[i-768];
  else if (i < 2304) o[i] = c[i-1536];
}

// ---------------- 256x256 BT-GEMM, BK=64, 8-phase counted-vmcnt schedule ----------------
// R14 (post-mortem R13): R13's port was null on FFN1 (MfmaUtil stuck at 20%).
// Root cause candidate: I wrapped EVERY s_barrier in sched_barrier(0) — 8 order-pins
// per K-tile. Guide m141: sched_barrier(0) order-pinning = 510 TF regression
// (defeats compiler scheduling); the verified m201 template uses RAW s_barrier in
// the K-loop with NO sched_barrier. R14 = remove the pins (single variable).
// Ordering safety: vmcnt asms keep "memory" clobber (stages can't cross them);
// raw-barrier pattern is the m201 HW-verified one.
// Geometry: BK=64 = 2 kk-halves; per K-tile 4 sub-phases x 16 MFMA, 2 barriers each.
// LDS 128KB: A buf c at c*32KB (2 halves x 16KB), B at 64KB + same. 1 block/CU.
// Staging ledger (one half-stage per phase): P1:A(t+1,h1) P2:B(t+1,h1)
// P3:A(t+2,h0) P4:B(t+2,h0)+vmcnt(4) -> tile t+1 landed, t+2-h0 in flight.
// Epilogue via LDS staging (b128 stores in >=64B runs; chunk-XOR conflict-free).
// SWZ=1 (K=768): per-XCD rt-fastest; SWZ=0 (K=3072 FFN2): ct-fastest.
template<int EPI, int SWZ>
__global__ __launch_bounds__(512, 2) void gemm256_k(
    const bf16* __restrict__ A, const bf16* __restrict__ Bt,
    const float* __restrict__ bias,
    bf16* __restrict__ outB, bf16* __restrict__ outK, bf16* __restrict__ outVT,
    int Nn, int K, int nct)
{
  __shared__ __align__(16) char lds[131072];
  const int t = threadIdx.x;
  const int lane = t & 63, w = t >> 6, g = lane >> 4, r = lane & 15;
  const int wr = w >> 2, wc = w & 3;
  const int lane16 = lane*16;

  const int cpx = gridDim.x >> 3;
  const int xcd = blockIdx.x & 7, loc = blockIdx.x >> 3;
  int rt, ct;
  if (SWZ) {                       // rt-fastest within the XCD's rt-slice
    const int nrt_x = cpx / nct;
    ct = loc / nrt_x;
    rt = xcd * nrt_x + (loc - ct*nrt_x);
  } else {                         // ct-fastest (FFN2: A panel resident)
    const int wg = xcd*cpx + loc;
    rt = wg / nct; ct = wg - rt*nct;
  }
  const size_t a0 = (size_t)rt*256, b0 = (size_t)ct*256;

  f32x4 acc[8][4];
  #pragma unroll
  for (int m=0;m<8;++m)
    #pragma unroll
    for (int n=0;n<4;++n) acc[m][n] = (f32x4){0.f,0.f,0.f,0.f};

  // staging bases: thread stages chunk (i*8+w)*64+lane of each 16KB half (i=0,1)
  const bf16* Asrc = A  + (a0 + w*16 + (lane&15))*(size_t)K + ((lane>>4)<<3);
  const bf16* Bsrc = Bt + (b0 + w*16 + (lane&15))*(size_t)K + ((lane>>4)<<3);
  char* dstA = lds + t*16;
  char* dstB = lds + 65536 + t*16;
  const size_t row128 = (size_t)128*K;
  const int NT = K >> 6;

#define SA_(k,h) do { const size_t so_ = (size_t)(k)*64 + (h)*32; \
    const int db_ = (((k)&1)<<15) + ((h)<<14); \
    gld_lds16(Asrc + so_,          dstA + db_); \
    gld_lds16(Asrc + row128 + so_, dstA + db_ + 8192); } while(0)
#define SB_(k,h) do { const size_t so_ = (size_t)(k)*64 + (h)*32; \
    const int db_ = (((k)&1)<<15) + ((h)<<14); \
    gld_lds16(Bsrc + so_,          dstB + db_); \
    gld_lds16(Bsrc + row128 + so_, dstB + db_ + 8192); } while(0)
#define BAR_ __builtin_amdgcn_s_barrier()
#define MFMA16_(mo) do { __builtin_amdgcn_s_setprio(1); \
    _Pragma("unroll") for (int m_=0;m_<4;++m_) \
      _Pragma("unroll") for (int n_=0;n_<4;++n_) \
        acc[(mo)+m_][n_] = __builtin_amdgcn_mfma_f32_16x16x32_bf16(af[m_], bfr[n_], acc[(mo)+m_][n_], 0, 0, 0); \
    __builtin_amdgcn_s_setprio(0); } while(0)

#define TILE_(tt, c) do { \
    const char* ABv = lds + (c)*32768 + (wr<<13) + lane16; \
    const char* BBv = lds + 65536 + (c)*32768 + (wc<<12) + lane16; \
    bf16x8 bfr[4], af[4]; \
    /* P1: kk0, m0-3 (+ stage A(t+1,h1)) */ \
    _Pragma("unroll") for (int n_=0;n_<4;++n_) bfr[n_] = *(const bf16x8*)(BBv + n_*1024); \
    _Pragma("unroll") for (int m_=0;m_<4;++m_) af[m_]  = *(const bf16x8*)(ABv + m_*1024); \
    if ((tt)+1 < NT) SA_((tt)+1, 1); \
    BAR_; MFMA16_(0); BAR_; \
    /* P2: kk0, m4-7 (reuse B kk0; stage B(t+1,h1)) */ \
    _Pragma("unroll") for (int m_=0;m_<4;++m_) af[m_] = *(const bf16x8*)(ABv + 4096 + m_*1024); \
    if ((tt)+1 < NT) SB_((tt)+1, 1); \
    BAR_; MFMA16_(4); BAR_; \
    /* P3: kk1, m0-3 (+ stage A(t+2,h0)) */ \
    _Pragma("unroll") for (int n_=0;n_<4;++n_) bfr[n_] = *(const bf16x8*)(BBv + 16384 + n_*1024); \
    _Pragma("unroll") for (int m_=0;m_<4;++m_) af[m_]  = *(const bf16x8*)(ABv + 16384 + m_*1024); \
    if ((tt)+2 < NT) SA_((tt)+2, 0); \
    BAR_; MFMA16_(0); BAR_; \
    /* P4: kk1, m4-7; stage B(t+2,h0); publish tile t+1 with counted vmcnt */ \
    _Pragma("unroll") for (int m_=0;m_<4;++m_) af[m_] = *(const bf16x8*)(ABv + 16384 + 4096 + m_*1024); \
    if ((tt)+2 < NT) { SB_((tt)+2, 0); \
      asm volatile("s_waitcnt vmcnt(4)" ::: "memory"); \
    } else if ((tt)+1 < NT) { \
      asm volatile("s_waitcnt vmcnt(0)" ::: "memory"); \
    } \
    BAR_; MFMA16_(4); BAR_; \
  } while(0)

  // prologue: tile0 (both halves) + tile1 h0; vmcnt(4) leaves tile1-h0 in flight
  SA_(0,0); SB_(0,0); SA_(0,1); SB_(0,1); SA_(1,0); SB_(1,0);
  asm volatile("s_waitcnt vmcnt(4)" ::: "memory");
  BAR_;

  for (int tt = 0; tt < NT; tt += 2) {
    TILE_(tt, 0);
    TILE_(tt+1, 1);
  }
#undef TILE_
#undef MFMA16_
#undef BAR_
#undef SB_
#undef SA_

  // ---------------- coalesced epilogue via LDS staging (2 half-tiles) ----------------
  const int rowb = rt*256;
  const int colb = ct*256;
  bf16* lds16p = (bf16*)lds;
  const int g4 = g*4;
  const bool vtile = (EPI == 4) && (ct >= 6);

  #pragma unroll
  for (int ph = 0; ph < 2; ++ph) {
    __builtin_amdgcn_s_barrier();        // previous phase / K-loop LDS reads complete
    #pragma unroll
    for (int n = 0; n < 4; ++n) {
      const int col = wc*64 + n*16 + r;
      const float bc = bias[colb + col];
      #pragma unroll
      for (int m = 0; m < 4; ++m) {
        #pragma unroll
        for (int j = 0; j < 4; ++j) {
          float v = acc[ph*4+m][n][j] + bc;
          if (EPI == 3) v = gelu_f(v);
          const int rowin = m*16 + g4 + j;              // 0..63 within this wr half
          if (vtile) {
            lds16p[col*128 + wr*64 + (rowin ^ ((col&7)<<3))] = (bf16)v;
          } else {
            const int rowL = wr*64 + rowin;             // 0..127
            const int chs = ((col>>3) ^ ((rowL>>2)&7)); // chunk-XOR: conflict-free writes
            lds16p[rowL*256 + (chs<<3) + (col&7)] = (bf16)v;
          }
        }
      }
    }
    __builtin_amdgcn_s_barrier();
    if (vtile) {
      #pragma unroll
      for (int i = 0; i < 8; ++i) {
        const int cid = i*512 + t;
        const int col = cid >> 4, chunk = cid & 15, run = chunk >> 3, k = chunk & 7;
        bf16x8 val = *(const bf16x8*)&lds16p[col*128 + run*64 + ((k ^ (col&7))<<3)];
        const int rowg = rowb + run*128 + ph*64 + k*8;
        const int s  = rowg >= R_;
        const int rr = rowg - s*R_;
        const int bb = rr / N_, nn = rr - bb*N_;
        bf16* p = outVT + (size_t)s*R_*D_ + ((size_t)bb*D_ + (ct-6)*256 + col)*N_ + nn;
        *(bf16x8*)p = val;                 // cached: consumed by attention
      }
    } else {
      #pragma unroll
      for (int i = 0; i < 8; ++i) {
        const int cid = i*512 + t;
        const int rl = cid >> 5, ch = cid & 31;
        bf16x8 val = *(const bf16x8*)&lds16p[rl*256 + ((ch ^ ((rl>>2)&7))<<3)];
        const int rowg = rowb + (rl>>6)*128 + ph*64 + (rl&63);
        const int c0 = colb + ch*8;
        if (EPI == 0 || EPI == 3) {
          *(bf16x8*)(outB + (size_t)rowg*Nn + c0) = val;   // cached intermediate
        } else {  // EPI==4 Q/K routing (8-col chunk never straddles a head: 96%8==0)
          const int s  = rowg >= R_;
          const int rr = rowg - s*R_;
          const int bb = rr / N_, nn = rr - bb*N_;
          const size_t so = (size_t)s*R_*D_;
          bf16* p;
          if (c0 < 768) {
            const int hh = c0/96, dd = c0 - hh*96;
            p = outB + so + ((size_t)(bb*H_+hh)*N_ + nn)*HD_ + dd;
          } else {
            const int c1 = c0 - 768;
            const int hh = c1/96, dd = c1 - hh*96;
            p = outK + so + ((size_t)(bb*H_+hh)*N_ + nn)*HD_ + dd;
          }
          *(bf16x8*)p = val;               // cached: consumed by attention
        }
      }
    }
  }
}

// ---------------- attention (R12 verbatim) ----------------
// Grid 2304, block 256 (4 waves). h = blk&7 (XCD pin), i = blk>>3, b = i/18, qt = i%18.
// Wave (wq, wc): 16 q-rows, 288-col half. Q,K head-sep [B][H][N][96]; VT [B][D][N].
// setprio(1) around each MFMA triple (R11: independent-wave regime, m191 +4-7%).
// R9 lesson kept: NO register-pressure-raising ILP here — latency-bound => TLP.

__global__ __launch_bounds__(256, 2) void attn_stats_k(
    const bf16* __restrict__ Q, const bf16* __restrict__ Kb,
    const bf16* __restrict__ VT, bf16* __restrict__ obuf,
    float* __restrict__ mrow, float* __restrict__ rrow)
{
  __shared__ __align__(16) char plds[2*18432 + 512];
  float* smax = (float*)(plds + 36864);
  float* ssum = smax + 64;
  const int t = threadIdx.x, w = t>>6, lane = t&63, g = lane>>4, r = lane&15;
  const int wq = w>>1, wc = w&1;
  const int h = blockIdx.x & 7, ii = blockIdx.x >> 3;
  const int b = ii/18, qt = ii - b*18, bh = b*8 + h;
  const int q0 = qt*32 + wq*16, c0 = wc*288, row4 = g*4;

  f32x4 s[18];
  #pragma unroll
  for (int n=0;n<18;++n) s[n] = (f32x4){0.f,0.f,0.f,0.f};
  bf16x8 aq[3];
  const bf16* qrow = Q + ((size_t)(b*H_+h)*N_ + q0 + r)*HD_;
  #pragma unroll
  for (int kk=0;kk<3;++kk) aq[kk] = *(const bf16x8*)(qrow + kk*32 + g*8);
  const bf16* kbase = Kb + ((size_t)(b*H_+h)*N_ + c0 + r)*HD_ + g*8;
  #pragma unroll
  for (int n=0;n<18;++n) {
    const bf16* kr = kbase + (size_t)(n*16)*HD_;
    bf16x8 b0 = *(const bf16x8*)(kr);
    bf16x8 b1 = *(const bf16x8*)(kr + 32);
    bf16x8 b2 = *(const bf16x8*)(kr + 64);
    __builtin_amdgcn_s_setprio(1);
    s[n] = __builtin_amdgcn_mfma_f32_16x16x32_bf16(aq[0], b0, s[n], 0, 0, 0);
    s[n] = __builtin_amdgcn_mfma_f32_16x16x32_bf16(aq[1], b1, s[n], 0, 0, 0);
    s[n] = __builtin_amdgcn_mfma_f32_16x16x32_bf16(aq[2], b2, s[n], 0, 0, 0);
    __builtin_amdgcn_s_setprio(0);
  }

  float mx[4], sum[4], rinv[4];
  #pragma unroll
  for (int j=0;j<4;++j) {
    float m = -1e30f;
    #pragma unroll
    for (int n=0;n<18;++n) m = fmaxf(m, s[n][j]);
    #pragma unroll
    for (int d=1; d<16; d<<=1) m = fmaxf(m, __shfl_xor(m, d));
    mx[j] = m;
  }
  if ((lane&15)==0) {
    #pragma unroll
    for (int j=0;j<4;++j) smax[(wq*2+wc)*16 + row4+j] = mx[j];
  }
  __syncthreads();
  #pragma unroll
  for (int j=0;j<4;++j) {
    mx[j] = fmaxf(mx[j], smax[(wq*2+(wc^1))*16 + row4+j]);
    sum[j] = 0.f;
  }
  #pragma unroll
  for (int n=0;n<18;++n)
    #pragma unroll
    for (int j=0;j<4;++j) {
      float p = __expf((s[n][j] - mx[j]) * SCALE_F);
      s[n][j] = p; sum[j] += p;
    }
  #pragma unroll
  for (int j=0;j<4;++j) {
    #pragma unroll
    for (int d=1; d<16; d<<=1) sum[j] += __shfl_xor(sum[j], d);
  }
  if ((lane&15)==0) {
    #pragma unroll
    for (int j=0;j<4;++j) ssum[(wq*2+wc)*16 + row4+j] = sum[j];
  }
  __syncthreads();
  #pragma unroll
  for (int j=0;j<4;++j)
    rinv[j] = 1.0f / (sum[j] + ssum[(wq*2+(wc^1))*16 + row4+j]);

  if (wc==0 && (lane&15)==0) {
    const size_t sb = (size_t)bh*N_ + q0 + row4;
    #pragma unroll
    for (int j=0;j<4;++j) { mrow[sb+j] = mx[j]; rrow[sb+j] = rinv[j]; }
  }

  char* pw = plds + wq*18432;
  #pragma unroll
  for (int n=0;n<18;++n)
    #pragma unroll
    for (int j=0;j<4;++j) {
      int kc = c0 + n*16 + r, row = row4 + j;
      *(bf16*)(pw + ((kc>>3)<<8) + (row<<4) + ((kc&7)<<1)) = (bf16)(s[n][j]*rinv[j]);
    }
  __syncthreads();

  f32x4 oa[3];
  #pragma unroll
  for (int n=0;n<3;++n) oa[n] = (f32x4){0.f,0.f,0.f,0.f};
  const bf16* vtb = VT + ((size_t)b*D_ + h*HD_ + wc*48 + r)*N_ + g*8;
  for (int kt=0; kt<18; ++kt) {
    bf16x8 pa = *(const bf16x8*)(pw + kt*1024 + lane*16);
    bf16x8 v0 = *(const bf16x8*)(vtb + kt*32);
    bf16x8 v1 = *(const bf16x8*)(vtb + (size_t)16*N_ + kt*32);
    bf16x8 v2 = *(const bf16x8*)(vtb + (size_t)32*N_ + kt*32);
    __builtin_amdgcn_s_setprio(1);
    oa[0] = __builtin_amdgcn_mfma_f32_16x16x32_bf16(pa, v0, oa[0], 0, 0, 0);
    oa[1] = __builtin_amdgcn_mfma_f32_16x16x32_bf16(pa, v1, oa[1], 0, 0, 0);
    oa[2] = __builtin_amdgcn_mfma_f32_16x16x32_bf16(pa, v2, oa[2], 0, 0, 0);
    __builtin_amdgcn_s_setprio(0);
  }
  #pragma unroll
  for (int n=0;n<3;++n)
    #pragma unroll
    for (int j=0;j<4;++j)
      obuf[((size_t)b*N_ + q0+row4+j)*D_ + h*HD_ + wc*48 + n*16 + r] = (bf16)oa[n][j];
}

__global__ __launch_bounds__(256, 2) void attn_map_k(
    const bf16* __restrict__ Q1, const bf16* __restrict__ K2,
    const bf16* __restrict__ VT2, const bf16* __restrict__ K1,
    const bf16* __restrict__ Q2, const float* __restrict__ mrow,
    const float* __restrict__ rrow, float* __restrict__ attn_out,
    bf16* __restrict__ obuf)
{
  __shared__ __align__(16) char plds[2*18432 + 512];
  float* smax = (float*)(plds + 36864);
  float* ssum = smax + 64;
  const int t = threadIdx.x, w = t>>6, lane = t&63, g = lane>>4, r = lane&15;
  const int wq = w>>1, wc = w&1;
  const int h = blockIdx.x & 7, ii = blockIdx.x >> 3;
  const int b = ii/18, qt = ii - b*18, bh = b*8 + h;
  const int q0 = qt*32 + wq*16, c0 = wc*288, row4 = g*4;

  f32x4 s[18];
  #pragma unroll
  for (int n=0;n<18;++n) s[n] = (f32x4){0.f,0.f,0.f,0.f};
  bf16x8 aq[3];
  const bf16* qrow = Q1 + ((size_t)(b*H_+h)*N_ + q0 + r)*HD_;
  #pragma unroll
  for (int kk=0;kk<3;++kk) aq[kk] = *(const bf16x8*)(qrow + kk*32 + g*8);
  const bf16* kbase = K2 + ((size_t)(b*H_+h)*N_ + c0 + r)*HD_ + g*8;
  #pragma unroll
  for (int n=0;n<18;++n) {
    const bf16* kr = kbase + (size_t)(n*16)*HD_;
    bf16x8 b0 = *(const bf16x8*)(kr);
    bf16x8 b1 = *(const bf16x8*)(kr + 32);
    bf16x8 b2 = *(const bf16x8*)(kr + 64);
    __builtin_amdgcn_s_setprio(1);
    s[n] = __builtin_amdgcn_mfma_f32_16x16x32_bf16(aq[0], b0, s[n], 0, 0, 0);
    s[n] = __builtin_amdgcn_mfma_f32_16x16x32_bf16(aq[1], b1, s[n], 0, 0, 0);
    s[n] = __builtin_amdgcn_mfma_f32_16x16x32_bf16(aq[2], b2, s[n], 0, 0, 0);
    __builtin_amdgcn_s_setprio(0);
  }

  float mx[4], sum[4], rinv[4];
  #pragma unroll
  for (int j=0;j<4;++j) {
    float m = -1e30f;
    #pragma unroll
    for (int n=0;n<18;++n) m = fmaxf(m, s[n][j]);
    #pragma unroll
    for (int d=1; d<16; d<<=1) m = fmaxf(m, __shfl_xor(m, d));
    mx[j] = m;
  }
  if ((lane&15)==0) {
    #pragma unroll
    for (int j=0;j<4;++j) smax[(wq*2+wc)*16 + row4+j] = mx[j];
  }
  __syncthreads();
  #pragma unroll
  for (int j=0;j<4;++j) {
    mx[j] = fmaxf(mx[j], smax[(wq*2+(wc^1))*16 + row4+j]);
    sum[j] = 0.f;
  }
  #pragma unroll
  for (int n=0;n<18;++n)
    #pragma unroll
    for (int j=0;j<4;++j) {
      float p = __expf((s[n][j] - mx[j]) * SCALE_F);
      s[n][j] = p; sum[j] += p;
    }
  #pragma unroll
  for (int j=0;j<4;++j) {
    #pragma unroll
    for (int d=1; d<16; d<<=1) sum[j] += __shfl_xor(sum[j], d);
  }
  if ((lane&15)==0) {
    #pragma unroll
    for (int j=0;j<4;++j) ssum[(wq*2+wc)*16 + row4+j] = sum[j];
  }
  __syncthreads();
  #pragma unroll
  for (int j=0;j<4;++j)
    rinv[j] = 1.0f / (sum[j] + ssum[(wq*2+(wc^1))*16 + row4+j]);

  char* pw = plds + wq*18432;
  #pragma unroll
  for (int n=0;n<18;++n)
    #pragma unroll
    for (int j=0;j<4;++j) {
      int kc = c0 + n*16 + r, row = row4 + j;
      *(bf16*)(pw + ((kc>>3)<<8) + (row<<4) + ((kc&7)<<1)) = (bf16)(s[n][j]*rinv[j]);
    }
  __syncthreads();

  f32x4 oa[3];
  #pragma unroll
  for (int n=0;n<3;++n) oa[n] = (f32x4){0.f,0.f,0.f,0.f};
  const bf16* vtb = VT2 + ((size_t)b*D_ + h*HD_ + wc*48 + r)*N_ + g*8;
  for (int kt=0; kt<18; ++kt) {
    bf16x8 pa = *(const bf16x8*)(pw + kt*1024 + lane*16);
    bf16x8 v0 = *(const bf16x8*)(vtb + kt*32);
    bf16x8 v1 = *(const bf16x8*)(vtb + (size_t)16*N_ + kt*32);
    bf16x8 v2 = *(const bf16x8*)(vtb + (size_t)32*N_ + kt*32);
    __builtin_amdgcn_s_setprio(1);
    oa[0] = __builtin_amdgcn_mfma_f32_16x16x32_bf16(pa, v0, oa[0], 0, 0, 0);
    oa[1] = __builtin_amdgcn_mfma_f32_16x16x32_bf16(pa, v1, oa[1], 0, 0, 0);
    oa[2] = __builtin_amdgcn_mfma_f32_16x16x32_bf16(pa, v2, oa[2], 0, 0, 0);
    __builtin_amdgcn_s_setprio(0);
  }
  #pragma unroll
  for (int n=0;n<3;++n)
    #pragma unroll
    for (int j=0;j<4;++j)
      obuf[((size_t)b*N_ + q0+row4+j)*D_ + h*HD_ + wc*48 + n*16 + r] = (bf16)oa[n][j];

  // T = K1 Q2^T over col-half (T[q][k] = S2[k][q]); reuse s accs
  #pragma unroll
  for (int n=0;n<18;++n) s[n] = (f32x4){0.f,0.f,0.f,0.f};
  bf16x8 ak[3];
  const bf16* k1row = K1 + ((size_t)(b*H_+h)*N_ + q0 + r)*HD_;
  #pragma unroll
  for (int kk=0;kk<3;++kk) ak[kk] = *(const bf16x8*)(k1row + kk*32 + g*8);
  const bf16* q2b = Q2 + ((size_t)(b*H_+h)*N_ + c0 + r)*HD_ + g*8;
  #pragma unroll
  for (int n=0;n<18;++n) {
    const bf16* qr2 = q2b + (size_t)(n*16)*HD_;
    bf16x8 b0 = *(const bf16x8*)(qr2);
    bf16x8 b1 = *(const bf16x8*)(qr2 + 32);
    bf16x8 b2 = *(const bf16x8*)(qr2 + 64);
    __builtin_amdgcn_s_setprio(1);
    s[n] = __builtin_amdgcn_mfma_f32_16x16x32_bf16(ak[0], b0, s[n], 0, 0, 0);
    s[n] = __builtin_amdgcn_mfma_f32_16x16x32_bf16(ak[1], b1, s[n], 0, 0, 0);
    s[n] = __builtin_amdgcn_mfma_f32_16x16x32_bf16(ak[2], b2, s[n], 0, 0, 0);
    __builtin_amdgcn_s_setprio(0);
  }

  const float* mb = mrow + (size_t)bh*N_;
  const float* rb = rrow + (size_t)bh*N_;
  float* aout = attn_out + (size_t)bh*N_*N_;
  #pragma unroll
  for (int n=0;n<18;++n) {
    const int kc = c0 + n*16 + r;
    const float m2v = mb[kc];
    const float rv  = rb[kc];
    #pragma unroll
    for (int j=0;j<4;++j) {
      const int row = row4 + j;
      float p1 = (float)(*(const bf16*)(pw + ((kc>>3)<<8) + (row<<4) + ((kc&7)<<1)));
      float a2t = __expf((s[n][j] - m2v) * SCALE_F) * rv;
      nt_f32(aout + (size_t)(q0 + row)*N_ + kc, 0.5f*(p1 + a2t));   // final output: nt
    }
  }
}

// ---------------- LayerNorm over 2R rows ----------------
// MODE 0: xres = f32 (x1/x2 per half), y = bf16 -> out bf16 (intermediate: cached)
// MODE 1: xres = bf16, y = bf16 -> out f32 (d_out: nt)
template<int MODE>
__global__ __launch_bounds__(256) void ln_k(
    const float* __restrict__ xf1, const float* __restrict__ xf2,
    const bf16* __restrict__ xb, const bf16* __restrict__ y,
    const float* __restrict__ gamma, const float* __restrict__ beta,
    bf16* __restrict__ out16, float* __restrict__ out32)
{
  const int w = threadIdx.x>>6, lane = threadIdx.x&63;
  const size_t row = (size_t)blockIdx.x*4 + w;
  float v[12]; float s = 0.f, s2 = 0.f;
  const bf16* yr = y + row*D_;
  #pragma unroll
  for (int i=0;i<3;++i) {
    int c = i*256 + lane*4;
    bf16x4 bb = *(const bf16x4*)(yr + c);
    float xr4[4];
    if (MODE == 0) {
      const float* xr = (row < R_) ? (xf1 + row*D_) : (xf2 + (row-R_)*D_);
      f32x4 a = *(const f32x4*)(xr + c);
      #pragma unroll
      for (int q=0;q<4;++q) xr4[q] = a[q];
    } else {
      bf16x4 a = *(const bf16x4*)(xb + row*D_ + c);
      #pragma unroll
      for (int q=0;q<4;++q) xr4[q] = (float)a[q];
    }
    #pragma unroll
    for (int q=0;q<4;++q) {
      float tq = xr4[q] + (float)bb[q];
      v[i*4+q] = tq; s += tq; s2 += tq*tq;
    }
  }
  #pragma unroll
  for (int d=1; d<64; d<<=1) { s += __shfl_xor(s, d); s2 += __shfl_xor(s2, d); }
  const float mean = s*(1.f/D_);
  const float var  = s2*(1.f/D_) - mean*mean;
  const float rstd = rsqrtf(var + 1e-5f);
  #pragma unroll
  for (int i=0;i<3;++i) {
    int c = i*256 + lane*4;
    f32x4 gm = *(const f32x4*)(gamma + c);
    f32x4 bt = *(const f32x4*)(beta  + c);
    float o[4];
    #pragma unroll
    for (int q=0;q<4;++q) o[q] = (v[i*4+q]-mean)*rstd*gm[q] + bt[q];
    if (MODE == 0) {
      union { bf16 h[4]; unsigned long long q64; } u;
      u.h[0]=(bf16)o[0]; u.h[1]=(bf16)o[1]; u.h[2]=(bf16)o[2]; u.h[3]=(bf16)o[3];
      *(unsigned long long*)(out16 + row*D_ + c) = u.q64;   // cached intermediate
    } else {
      f32x4 ov = {o[0], o[1], o[2], o[3]};
      __builtin_nontemporal_store(ov, (f32x4*)(out32 + row*D_ + c));  // d_out: nt
    }
  }
}

// ---------------- host ----------------
extern "C" void kernel_launch(void* const* d_in, const int* in_sizes, int n_in,
                              void* d_out, int out_size, void* d_ws, size_t ws_size,
                              hipStream_t stream)
{
  const float* x1  = (const float*)d_in[0];
  const float* x2  = (const float*)d_in[1];
  const float* Wq  = (const float*)d_in[2];  const float* bq  = (const float*)d_in[3];
  const float* Wk  = (const float*)d_in[4];  const float* bk  = (const float*)d_in[5];
  const float* Wv  = (const float*)d_in[6];  const float* bv  = (const float*)d_in[7];
  const float* Wo  = (const float*)d_in[8];  const float* bo  = (const float*)d_in[9];
  const float* g1  = (const float*)d_in[10]; const float* be1 = (const float*)d_in[11];
  const float* g2  = (const float*)d_in[12]; const float* be2 = (const float*)d_in[13];
  const float* W1  = (const float*)d_in[14]; const float* bf1 = (const float*)d_in[15];
  const float* W2  = (const float*)d_in[16]; const float* bf2 = (const float*)d_in[17];

  float* outLN = (float*)d_out;                     // [2R][D] = out1 | out2
  float* attn  = outLN + (size_t)2*R_*D_;

  char* ws = (char*)d_ws;
  size_t off = 0;
  auto alloc = [&](size_t bytes) -> void* {
    void* p = ws + off;
    off += (bytes + 255) & ~(size_t)255;
    return p;
  };
  const size_t RD2 = (size_t)R_*D_*2;               // one block's bf16 [R][D]
  // span1: xb | Q | K | VT  (4 x 2RD2 = 113.2MB) — aliased by G later
  size_t span1 = off;
  bf16* xb  = (bf16*)alloc(2*RD2);
  bf16* Qb  = (bf16*)alloc(2*RD2);
  bf16* Kb  = (bf16*)alloc(2*RD2);
  bf16* VTb = (bf16*)alloc(2*RD2);
  bf16* G   = (bf16*)(ws + span1);                  // [2R][DF] bf16 = 113.2MB, fits span1
  bf16* wqkvT = (bf16*)alloc((size_t)2304*D_*2);
  float* bqkv = (float*)alloc(2304*4);
  bf16* woT   = (bf16*)alloc((size_t)D_*D_*2);
  bf16* w1T   = (bf16*)alloc((size_t)D_*DF_*2);
  bf16* w2T   = (bf16*)alloc((size_t)DF_*D_*2);
  bf16* obuf  = (bf16*)alloc(2*RD2);
  bf16* oprojB= (bf16*)alloc(2*RD2);
  bf16* h16   = (bf16*)alloc(2*RD2);
  bf16* f16   = (bf16*)alloc(2*RD2);
  float* m2r  = (float*)alloc((size_t)B_*H_*N_*4);
  float* r2r  = (float*)alloc((size_t)B_*H_*N_*4);
  (void)ws_size; (void)in_sizes; (void)n_in; (void)out_size;

  const int n4 = R_*D_/4;
  cast_f32_bf16_k<<<n4/256, 256, 0, stream>>>(x1, xb, n4);
  cast_f32_bf16_k<<<n4/256, 256, 0, stream>>>(x2, xb + (size_t)R_*D_, n4);

  dim3 tb(32,8);
  transpose_cast_k<<<dim3(24,24), tb, 0, stream>>>(Wq, wqkvT,             D_, D_);
  transpose_cast_k<<<dim3(24,24), tb, 0, stream>>>(Wk, wqkvT + 768*D_,    D_, D_);
  transpose_cast_k<<<dim3(24,24), tb, 0, stream>>>(Wv, wqkvT + 1536*D_,   D_, D_);
  transpose_cast_k<<<dim3(24,24), tb, 0, stream>>>(Wo, woT, D_, D_);
  transpose_cast_k<<<dim3(96,24), tb, 0, stream>>>(W1, w1T, D_, DF_);   // -> [3072][768]
  transpose_cast_k<<<dim3(24,96), tb, 0, stream>>>(W2, w2T, DF_, D_);   // -> [768][3072]
  concat_bias_k<<<9, 256, 0, stream>>>(bq, bk, bv, bqkv);

  // fused QKV for BOTH inputs: M=2R=18432, N=2304, K=768 -> grid 72x9=648
  gemm256_k<4,1><<<648, 512, 0, stream>>>(xb, wqkvT, bqkv, Qb, Kb, VTb, 2304, 768, 9);

  // attention (per-s pointers into combined buffers)
  const size_t SD = (size_t)R_*D_;
  attn_stats_k<<<2304, 256, 0, stream>>>(Qb + SD, Kb, VTb, obuf + SD, m2r, r2r);
  attn_map_k  <<<2304, 256, 0, stream>>>(Qb, Kb + SD, VTb + SD, Kb, Qb + SD, m2r, r2r, attn, obuf);

  // combined tails: M=2R for all
  gemm256_k<0,1><<<216, 512, 0, stream>>>(obuf, woT, bo, oprojB, nullptr, nullptr, 768, 768, 3);
  ln_k<0><<<2*R_/4, 256, 0, stream>>>(x1, x2, nullptr, oprojB, g1, be1, h16, nullptr);
  gemm256_k<3,1><<<864, 512, 0, stream>>>(h16, w1T, bf1, G, nullptr, nullptr, 3072, 768, 12);
  gemm256_k<0,0><<<216, 512, 0, stream>>>(G, w2T, bf2, f16, nullptr, nullptr, 768, 3072, 3);
  ln_k<1><<<2*R_/4, 256, 0, stream>>>(nullptr, nullptr, h16, f16, g2, be2, nullptr, outLN);
}

// Round 15
// 701.607 us; speedup vs baseline: 1.0080x; 1.0080x over previous
//
#include <hip/hip_runtime.h>
#include <cstdint>
#include <cstddef>

// Problem constants
#define B_   16
#define N_   576
#define D_   768
#define H_   8
#define HD_  96
#define DF_  3072
#define R_   (B_*N_)               // 9216 rows per block-input; 2R = 18432 combined
#define SCALE_F 0.10206207261596575f  // 96^-0.5

typedef __bf16 bf16;
typedef __attribute__((ext_vector_type(8))) __bf16 bf16x8;
typedef __attribute__((ext_vector_type(4))) __bf16 bf16x4;
typedef __attribute__((ext_vector_type(4))) float  f32x4;

__device__ __forceinline__ void gld_lds16(const void* g, void* l) {
  __builtin_amdgcn_global_load_lds((const __attribute__((address_space(1))) void*)g,
                                   (__attribute__((address_space(3))) void*)l,
                                   16, 0, 0);
}
__device__ __forceinline__ void nt_f32(float* p, float v) { __builtin_nontemporal_store(v, p); }
// tanh-form gelu (max dev vs exact erf-gelu ~3e-3; threshold 0.104, current absmax 0.031)
__device__ __forceinline__ float gelu_f(float v) {
  float u = 0.7978845608028654f * v * (1.0f + 0.044715f*v*v);
  float e = __expf(2.0f*u);                  // overflow->inf is fine (th->1)
  float th = 1.0f - 2.0f/(e + 1.0f);
  return 0.5f*v*(1.0f + th);
}

// ---------------- prep kernels ----------------
__global__ void cast_f32_bf16_k(const float* __restrict__ x, bf16* __restrict__ y, int n4) {
  int i = blockIdx.x*256 + threadIdx.x;
  if (i >= n4) return;
  f32x4 v = ((const f32x4*)x)[i];
  union { bf16 h[4]; unsigned long long q; } u;
  u.h[0] = (bf16)v[0]; u.h[1] = (bf16)v[1]; u.h[2] = (bf16)v[2]; u.h[3] = (bf16)v[3];
  ((unsigned long long*)y)[i] = u.q;         // cached: consumed by QKV GEMM
}

// WT[c][r] = (bf16)W[r][c];  rows, cols multiples of 32
__global__ void transpose_cast_k(const float* __restrict__ W, bf16* __restrict__ WT,
                                 int rows, int cols) {
  __shared__ float tile[32][33];
  int cb = blockIdx.x*32, rb = blockIdx.y*32;
  int tx = threadIdx.x, ty = threadIdx.y;   // block (32,8)
  #pragma unroll
  for (int i=0;i<32;i+=8)
    tile[ty+i][tx] = W[(size_t)(rb+ty+i)*cols + cb+tx];
  __syncthreads();
  #pragma unroll
  for (int i=0;i<32;i+=8)
    WT[(size_t)(cb+ty+i)*rows + rb+tx] = (bf16)tile[tx][ty+i];
}

__global__ void concat_bias_k(const float* a, const float* b, const float* c, float* o) {
  int i = blockIdx.x*256 + threadIdx.x;
  if (i < 768) o[i] = a[i];
  else if (i < 1536) o[i] = b[i-768];
  else if (i < 2304) o[i] = c[i-1536];
}

// ---------------- 256x256 BT-GEMM, BK=64, 8-phase split-wait schedule ----------------
// R15 (post-mortem R14): R13/R14's single vmcnt(4) at P4 forced tile t+1's h1
// (issued P1/P2 of the SAME tile, only ~2 phases earlier) to complete — a
// premature wait stalling every wave every tile. Staging depth was fine
// (data staged 5-6 phases before its ds_read); only the wait was early.
// Fix: TWO counted waits per tile, each requiring only loads issued 4-5
// phases earlier:
//   end-P2: vmcnt(8) -> completes SA/SB(t,h1)   [issued P1/P2(t-1); read at P3(t)]
//   end-P4: vmcnt(8) -> completes SA/SB(t+1,h0) [issued P3/P4(t-1); read at P1(t+1)]
// Each wait sits AFTER that phase's MFMA and BEFORE the barrier that precedes
// the dependent ds_reads (per-wave vmcnt + following s_barrier = cross-wave
// visibility). Tails: P2 -> vmcnt(0) when no stages remain; P4 -> vmcnt(4)
// when only t+1's stages outstanding. Prologue wait 4 -> 8 (tile0 h0 only;
// tile0 h1 is covered by P2(0)'s wait).
// Geometry unchanged: BK=64 = 2 kk-halves; 4 sub-phases x 16 MFMA, raw barriers.
// LDS 128KB: A buf c at c*32KB (2 halves x 16KB), B at 64KB + same. 1 block/CU.
// Stages: P1:A(t+1,h1) P2:B(t+1,h1) P3:A(t+2,h0) P4:B(t+2,h0).
// Epilogue via LDS staging (b128 stores in >=64B runs; chunk-XOR conflict-free).
// SWZ=1 (K=768): per-XCD rt-fastest; SWZ=0 (K=3072 FFN2): ct-fastest.
template<int EPI, int SWZ>
__global__ __launch_bounds__(512, 2) void gemm256_k(
    const bf16* __restrict__ A, const bf16* __restrict__ Bt,
    const float* __restrict__ bias,
    bf16* __restrict__ outB, bf16* __restrict__ outK, bf16* __restrict__ outVT,
    int Nn, int K, int nct)
{
  __shared__ __align__(16) char lds[131072];
  const int t = threadIdx.x;
  const int lane = t & 63, w = t >> 6, g = lane >> 4, r = lane & 15;
  const int wr = w >> 2, wc = w & 3;
  const int lane16 = lane*16;

  const int cpx = gridDim.x >> 3;
  const int xcd = blockIdx.x & 7, loc = blockIdx.x >> 3;
  int rt, ct;
  if (SWZ) {                       // rt-fastest within the XCD's rt-slice
    const int nrt_x = cpx / nct;
    ct = loc / nrt_x;
    rt = xcd * nrt_x + (loc - ct*nrt_x);
  } else {                         // ct-fastest (FFN2: A panel resident)
    const int wg = xcd*cpx + loc;
    rt = wg / nct; ct = wg - rt*nct;
  }
  const size_t a0 = (size_t)rt*256, b0 = (size_t)ct*256;

  f32x4 acc[8][4];
  #pragma unroll
  for (int m=0;m<8;++m)
    #pragma unroll
    for (int n=0;n<4;++n) acc[m][n] = (f32x4){0.f,0.f,0.f,0.f};

  // staging bases: thread stages chunk (i*8+w)*64+lane of each 16KB half (i=0,1)
  const bf16* Asrc = A  + (a0 + w*16 + (lane&15))*(size_t)K + ((lane>>4)<<3);
  const bf16* Bsrc = Bt + (b0 + w*16 + (lane&15))*(size_t)K + ((lane>>4)<<3);
  char* dstA = lds + t*16;
  char* dstB = lds + 65536 + t*16;
  const size_t row128 = (size_t)128*K;
  const int NT = K >> 6;

#define SA_(k,h) do { const size_t so_ = (size_t)(k)*64 + (h)*32; \
    const int db_ = (((k)&1)<<15) + ((h)<<14); \
    gld_lds16(Asrc + so_,          dstA + db_); \
    gld_lds16(Asrc + row128 + so_, dstA + db_ + 8192); } while(0)
#define SB_(k,h) do { const size_t so_ = (size_t)(k)*64 + (h)*32; \
    const int db_ = (((k)&1)<<15) + ((h)<<14); \
    gld_lds16(Bsrc + so_,          dstB + db_); \
    gld_lds16(Bsrc + row128 + so_, dstB + db_ + 8192); } while(0)
#define BAR_ __builtin_amdgcn_s_barrier()
#define MFMA16_(mo) do { __builtin_amdgcn_s_setprio(1); \
    _Pragma("unroll") for (int m_=0;m_<4;++m_) \
      _Pragma("unroll") for (int n_=0;n_<4;++n_) \
        acc[(mo)+m_][n_] = __builtin_amdgcn_mfma_f32_16x16x32_bf16(af[m_], bfr[n_], acc[(mo)+m_][n_], 0, 0, 0); \
    __builtin_amdgcn_s_setprio(0); } while(0)

#define TILE_(tt, c) do { \
    const char* ABv = lds + (c)*32768 + (wr<<13) + lane16; \
    const char* BBv = lds + 65536 + (c)*32768 + (wc<<12) + lane16; \
    bf16x8 bfr[4], af[4]; \
    /* P1: kk0, m0-3 (+ stage A(t+1,h1)) */ \
    _Pragma("unroll") for (int n_=0;n_<4;++n_) bfr[n_] = *(const bf16x8*)(BBv + n_*1024); \
    _Pragma("unroll") for (int m_=0;m_<4;++m_) af[m_]  = *(const bf16x8*)(ABv + m_*1024); \
    if ((tt)+1 < NT) SA_((tt)+1, 1); \
    BAR_; MFMA16_(0); BAR_; \
    /* P2: kk0, m4-7 (reuse B kk0; stage B(t+1,h1)); wait for tile t h1 */ \
    _Pragma("unroll") for (int m_=0;m_<4;++m_) af[m_] = *(const bf16x8*)(ABv + 4096 + m_*1024); \
    if ((tt)+1 < NT) SB_((tt)+1, 1); \
    BAR_; MFMA16_(4); \
    if ((tt)+1 < NT) { asm volatile("s_waitcnt vmcnt(8)" ::: "memory"); } \
    else             { asm volatile("s_waitcnt vmcnt(0)" ::: "memory"); } \
    BAR_; \
    /* P3: kk1, m0-3 (+ stage A(t+2,h0)) */ \
    _Pragma("unroll") for (int n_=0;n_<4;++n_) bfr[n_] = *(const bf16x8*)(BBv + 16384 + n_*1024); \
    _Pragma("unroll") for (int m_=0;m_<4;++m_) af[m_]  = *(const bf16x8*)(ABv + 16384 + m_*1024); \
    if ((tt)+2 < NT) SA_((tt)+2, 0); \
    BAR_; MFMA16_(0); BAR_; \
    /* P4: kk1, m4-7; stage B(t+2,h0); wait for tile t+1 h0 */ \
    _Pragma("unroll") for (int m_=0;m_<4;++m_) af[m_] = *(const bf16x8*)(ABv + 16384 + 4096 + m_*1024); \
    if ((tt)+2 < NT) SB_((tt)+2, 0); \
    BAR_; MFMA16_(4); \
    if ((tt)+2 < NT)      { asm volatile("s_waitcnt vmcnt(8)" ::: "memory"); } \
    else if ((tt)+1 < NT) { asm volatile("s_waitcnt vmcnt(4)" ::: "memory"); } \
    BAR_; \
  } while(0)

  // prologue: tile0 (both halves) + tile1 h0; vmcnt(8) completes tile0 h0 only
  // (tile0 h1 is enforced by P2(0)'s wait; tile1 h0 by P4(0)'s wait)
  SA_(0,0); SB_(0,0); SA_(0,1); SB_(0,1); SA_(1,0); SB_(1,0);
  asm volatile("s_waitcnt vmcnt(8)" ::: "memory");
  BAR_;

  for (int tt = 0; tt < NT; tt += 2) {
    TILE_(tt, 0);
    TILE_(tt+1, 1);
  }
#undef TILE_
#undef MFMA16_
#undef BAR_
#undef SB_
#undef SA_

  // ---------------- coalesced epilogue via LDS staging (2 half-tiles) ----------------
  const int rowb = rt*256;
  const int colb = ct*256;
  bf16* lds16p = (bf16*)lds;
  const int g4 = g*4;
  const bool vtile = (EPI == 4) && (ct >= 6);

  #pragma unroll
  for (int ph = 0; ph < 2; ++ph) {
    __builtin_amdgcn_s_barrier();        // previous phase / K-loop LDS reads complete
    #pragma unroll
    for (int n = 0; n < 4; ++n) {
      const int col = wc*64 + n*16 + r;
      const float bc = bias[colb + col];
      #pragma unroll
      for (int m = 0; m < 4; ++m) {
        #pragma unroll
        for (int j = 0; j < 4; ++j) {
          float v = acc[ph*4+m][n][j] + bc;
          if (EPI == 3) v = gelu_f(v);
          const int rowin = m*16 + g4 + j;              // 0..63 within this wr half
          if (vtile) {
            lds16p[col*128 + wr*64 + (rowin ^ ((col&7)<<3))] = (bf16)v;
          } else {
            const int rowL = wr*64 + rowin;             // 0..127
            const int chs = ((col>>3) ^ ((rowL>>2)&7)); // chunk-XOR: conflict-free writes
            lds16p[rowL*256 + (chs<<3) + (col&7)] = (bf16)v;
          }
        }
      }
    }
    __builtin_amdgcn_s_barrier();
    if (vtile) {
      #pragma unroll
      for (int i = 0; i < 8; ++i) {
        const int cid = i*512 + t;
        const int col = cid >> 4, chunk = cid & 15, run = chunk >> 3, k = chunk & 7;
        bf16x8 val = *(const bf16x8*)&lds16p[col*128 + run*64 + ((k ^ (col&7))<<3)];
        const int rowg = rowb + run*128 + ph*64 + k*8;
        const int s  = rowg >= R_;
        const int rr = rowg - s*R_;
        const int bb = rr / N_, nn = rr - bb*N_;
        bf16* p = outVT + (size_t)s*R_*D_ + ((size_t)bb*D_ + (ct-6)*256 + col)*N_ + nn;
        *(bf16x8*)p = val;                 // cached: consumed by attention
      }
    } else {
      #pragma unroll
      for (int i = 0; i < 8; ++i) {
        const int cid = i*512 + t;
        const int rl = cid >> 5, ch = cid & 31;
        bf16x8 val = *(const bf16x8*)&lds16p[rl*256 + ((ch ^ ((rl>>2)&7))<<3)];
        const int rowg = rowb + (rl>>6)*128 + ph*64 + (rl&63);
        const int c0 = colb + ch*8;
        if (EPI == 0 || EPI == 3) {
          *(bf16x8*)(outB + (size_t)rowg*Nn + c0) = val;   // cached intermediate
        } else {  // EPI==4 Q/K routing (8-col chunk never straddles a head: 96%8==0)
          const int s  = rowg >= R_;
          const int rr = rowg - s*R_;
          const int bb = rr / N_, nn = rr - bb*N_;
          const size_t so = (size_t)s*R_*D_;
          bf16* p;
          if (c0 < 768) {
            const int hh = c0/96, dd = c0 - hh*96;
            p = outB + so + ((size_t)(bb*H_+hh)*N_ + nn)*HD_ + dd;
          } else {
            const int c1 = c0 - 768;
            const int hh = c1/96, dd = c1 - hh*96;
            p = outK + so + ((size_t)(bb*H_+hh)*N_ + nn)*HD_ + dd;
          }
          *(bf16x8*)p = val;               // cached: consumed by attention
        }
      }
    }
  }
}

// ---------------- attention (R12 verbatim) ----------------
// Grid 2304, block 256 (4 waves). h = blk&7 (XCD pin), i = blk>>3, b = i/18, qt = i%18.
// Wave (wq, wc): 16 q-rows, 288-col half. Q,K head-sep [B][H][N][96]; VT [B][D][N].
// setprio(1) around each MFMA triple (R11: independent-wave regime, m191 +4-7%).
// R9 lesson kept: NO register-pressure-raising ILP here — latency-bound => TLP.

__global__ __launch_bounds__(256, 2) void attn_stats_k(
    const bf16* __restrict__ Q, const bf16* __restrict__ Kb,
    const bf16* __restrict__ VT, bf16* __restrict__ obuf,
    float* __restrict__ mrow, float* __restrict__ rrow)
{
  __shared__ __align__(16) char plds[2*18432 + 512];
  float* smax = (float*)(plds + 36864);
  float* ssum = smax + 64;
  const int t = threadIdx.x, w = t>>6, lane = t&63, g = lane>>4, r = lane&15;
  const int wq = w>>1, wc = w&1;
  const int h = blockIdx.x & 7, ii = blockIdx.x >> 3;
  const int b = ii/18, qt = ii - b*18, bh = b*8 + h;
  const int q0 = qt*32 + wq*16, c0 = wc*288, row4 = g*4;

  f32x4 s[18];
  #pragma unroll
  for (int n=0;n<18;++n) s[n] = (f32x4){0.f,0.f,0.f,0.f};
  bf16x8 aq[3];
  const bf16* qrow = Q + ((size_t)(b*H_+h)*N_ + q0 + r)*HD_;
  #pragma unroll
  for (int kk=0;kk<3;++kk) aq[kk] = *(const bf16x8*)(qrow + kk*32 + g*8);
  const bf16* kbase = Kb + ((size_t)(b*H_+h)*N_ + c0 + r)*HD_ + g*8;
  #pragma unroll
  for (int n=0;n<18;++n) {
    const bf16* kr = kbase + (size_t)(n*16)*HD_;
    bf16x8 b0 = *(const bf16x8*)(kr);
    bf16x8 b1 = *(const bf16x8*)(kr + 32);
    bf16x8 b2 = *(const bf16x8*)(kr + 64);
    __builtin_amdgcn_s_setprio(1);
    s[n] = __builtin_amdgcn_mfma_f32_16x16x32_bf16(aq[0], b0, s[n], 0, 0, 0);
    s[n] = __builtin_amdgcn_mfma_f32_16x16x32_bf16(aq[1], b1, s[n], 0, 0, 0);
    s[n] = __builtin_amdgcn_mfma_f32_16x16x32_bf16(aq[2], b2, s[n], 0, 0, 0);
    __builtin_amdgcn_s_setprio(0);
  }

  float mx[4], sum[4], rinv[4];
  #pragma unroll
  for (int j=0;j<4;++j) {
    float m = -1e30f;
    #pragma unroll
    for (int n=0;n<18;++n) m = fmaxf(m, s[n][j]);
    #pragma unroll
    for (int d=1; d<16; d<<=1) m = fmaxf(m, __shfl_xor(m, d));
    mx[j] = m;
  }
  if ((lane&15)==0) {
    #pragma unroll
    for (int j=0;j<4;++j) smax[(wq*2+wc)*16 + row4+j] = mx[j];
  }
  __syncthreads();
  #pragma unroll
  for (int j=0;j<4;++j) {
    mx[j] = fmaxf(mx[j], smax[(wq*2+(wc^1))*16 + row4+j]);
    sum[j] = 0.f;
  }
  #pragma unroll
  for (int n=0;n<18;++n)
    #pragma unroll
    for (int j=0;j<4;++j) {
      float p = __expf((s[n][j] - mx[j]) * SCALE_F);
      s[n][j] = p; sum[j] += p;
    }
  #pragma unroll
  for (int j=0;j<4;++j) {
    #pragma unroll
    for (int d=1; d<16; d<<=1) sum[j] += __shfl_xor(sum[j], d);
  }
  if ((lane&15)==0) {
    #pragma unroll
    for (int j=0;j<4;++j) ssum[(wq*2+wc)*16 + row4+j] = sum[j];
  }
  __syncthreads();
  #pragma unroll
  for (int j=0;j<4;++j)
    rinv[j] = 1.0f / (sum[j] + ssum[(wq*2+(wc^1))*16 + row4+j]);

  if (wc==0 && (lane&15)==0) {
    const size_t sb = (size_t)bh*N_ + q0 + row4;
    #pragma unroll
    for (int j=0;j<4;++j) { mrow[sb+j] = mx[j]; rrow[sb+j] = rinv[j]; }
  }

  char* pw = plds + wq*18432;
  #pragma unroll
  for (int n=0;n<18;++n)
    #pragma unroll
    for (int j=0;j<4;++j) {
      int kc = c0 + n*16 + r, row = row4 + j;
      *(bf16*)(pw + ((kc>>3)<<8) + (row<<4) + ((kc&7)<<1)) = (bf16)(s[n][j]*rinv[j]);
    }
  __syncthreads();

  f32x4 oa[3];
  #pragma unroll
  for (int n=0;n<3;++n) oa[n] = (f32x4){0.f,0.f,0.f,0.f};
  const bf16* vtb = VT + ((size_t)b*D_ + h*HD_ + wc*48 + r)*N_ + g*8;
  for (int kt=0; kt<18; ++kt) {
    bf16x8 pa = *(const bf16x8*)(pw + kt*1024 + lane*16);
    bf16x8 v0 = *(const bf16x8*)(vtb + kt*32);
    bf16x8 v1 = *(const bf16x8*)(vtb + (size_t)16*N_ + kt*32);
    bf16x8 v2 = *(const bf16x8*)(vtb + (size_t)32*N_ + kt*32);
    __builtin_amdgcn_s_setprio(1);
    oa[0] = __builtin_amdgcn_mfma_f32_16x16x32_bf16(pa, v0, oa[0], 0, 0, 0);
    oa[1] = __builtin_amdgcn_mfma_f32_16x16x32_bf16(pa, v1, oa[1], 0, 0, 0);
    oa[2] = __builtin_amdgcn_mfma_f32_16x16x32_bf16(pa, v2, oa[2], 0, 0, 0);
    __builtin_amdgcn_s_setprio(0);
  }
  #pragma unroll
  for (int n=0;n<3;++n)
    #pragma unroll
    for (int j=0;j<4;++j)
      obuf[((size_t)b*N_ + q0+row4+j)*D_ + h*HD_ + wc*48 + n*16 + r] = (bf16)oa[n][j];
}

__global__ __launch_bounds__(256, 2) void attn_map_k(
    const bf16* __restrict__ Q1, const bf16* __restrict__ K2,
    const bf16* __restrict__ VT2, const bf16* __restrict__ K1,
    const bf16* __restrict__ Q2, const float* __restrict__ mrow,
    const float* __restrict__ rrow, float* __restrict__ attn_out,
    bf16* __restrict__ obuf)
{
  __shared__ __align__(16) char plds[2*18432 + 512];
  float* smax = (float*)(plds + 36864);
  float* ssum = smax + 64;
  const int t = threadIdx.x, w = t>>6, lane = t&63, g = lane>>4, r = lane&15;
  const int wq = w>>1, wc = w&1;
  const int h = blockIdx.x & 7, ii = blockIdx.x >> 3;
  const int b = ii/18, qt = ii - b*18, bh = b*8 + h;
  const int q0 = qt*32 + wq*16, c0 = wc*288, row4 = g*4;

  f32x4 s[18];
  #pragma unroll
  for (int n=0;n<18;++n) s[n] = (f32x4){0.f,0.f,0.f,0.f};
  bf16x8 aq[3];
  const bf16* qrow = Q1 + ((size_t)(b*H_+h)*N_ + q0 + r)*HD_;
  #pragma unroll
  for (int kk=0;kk<3;++kk) aq[kk] = *(const bf16x8*)(qrow + kk*32 + g*8);
  const bf16* kbase = K2 + ((size_t)(b*H_+h)*N_ + c0 + r)*HD_ + g*8;
  #pragma unroll
  for (int n=0;n<18;++n) {
    const bf16* kr = kbase + (size_t)(n*16)*HD_;
    bf16x8 b0 = *(const bf16x8*)(kr);
    bf16x8 b1 = *(const bf16x8*)(kr + 32);
    bf16x8 b2 = *(const bf16x8*)(kr + 64);
    __builtin_amdgcn_s_setprio(1);
    s[n] = __builtin_amdgcn_mfma_f32_16x16x32_bf16(aq[0], b0, s[n], 0, 0, 0);
    s[n] = __builtin_amdgcn_mfma_f32_16x16x32_bf16(aq[1], b1, s[n], 0, 0, 0);
    s[n] = __builtin_amdgcn_mfma_f32_16x16x32_bf16(aq[2], b2, s[n], 0, 0, 0);
    __builtin_amdgcn_s_setprio(0);
  }

  float mx[4], sum[4], rinv[4];
  #pragma unroll
  for (int j=0;j<4;++j) {
    float m = -1e30f;
    #pragma unroll
    for (int n=0;n<18;++n) m = fmaxf(m, s[n][j]);
    #pragma unroll
    for (int d=1; d<16; d<<=1) m = fmaxf(m, __shfl_xor(m, d));
    mx[j] = m;
  }
  if ((lane&15)==0) {
    #pragma unroll
    for (int j=0;j<4;++j) smax[(wq*2+wc)*16 + row4+j] = mx[j];
  }
  __syncthreads();
  #pragma unroll
  for (int j=0;j<4;++j) {
    mx[j] = fmaxf(mx[j], smax[(wq*2+(wc^1))*16 + row4+j]);
    sum[j] = 0.f;
  }
  #pragma unroll
  for (int n=0;n<18;++n)
    #pragma unroll
    for (int j=0;j<4;++j) {
      float p = __expf((s[n][j] - mx[j]) * SCALE_F);
      s[n][j] = p; sum[j] += p;
    }
  #pragma unroll
  for (int j=0;j<4;++j) {
    #pragma unroll
    for (int d=1; d<16; d<<=1) sum[j] += __shfl_xor(sum[j], d);
  }
  if ((lane&15)==0) {
    #pragma unroll
    for (int j=0;j<4;++j) ssum[(wq*2+wc)*16 + row4+j] = sum[j];
  }
  __syncthreads();
  #pragma unroll
  for (int j=0;j<4;++j)
    rinv[j] = 1.0f / (sum[j] + ssum[(wq*2+(wc^1))*16 + row4+j]);

  char* pw = plds + wq*18432;
  #pragma unroll
  for (int n=0;n<18;++n)
    #pragma unroll
    for (int j=0;j<4;++j) {
      int kc = c0 + n*16 + r, row = row4 + j;
      *(bf16*)(pw + ((kc>>3)<<8) + (row<<4) + ((kc&7)<<1)) = (bf16)(s[n][j]*rinv[j]);
    }
  __syncthreads();

  f32x4 oa[3];
  #pragma unroll
  for (int n=0;n<3;++n) oa[n] = (f32x4){0.f,0.f,0.f,0.f};
  const bf16* vtb = VT2 + ((size_t)b*D_ + h*HD_ + wc*48 + r)*N_ + g*8;
  for (int kt=0; kt<18; ++kt) {
    bf16x8 pa = *(const bf16x8*)(pw + kt*1024 + lane*16);
    bf16x8 v0 = *(const bf16x8*)(vtb + kt*32);
    bf16x8 v1 = *(const bf16x8*)(vtb + (size_t)16*N_ + kt*32);
    bf16x8 v2 = *(const bf16x8*)(vtb + (size_t)32*N_ + kt*32);
    __builtin_amdgcn_s_setprio(1);
    oa[0] = __builtin_amdgcn_mfma_f32_16x16x32_bf16(pa, v0, oa[0], 0, 0, 0);
    oa[1] = __builtin_amdgcn_mfma_f32_16x16x32_bf16(pa, v1, oa[1], 0, 0, 0);
    oa[2] = __builtin_amdgcn_mfma_f32_16x16x32_bf16(pa, v2, oa[2], 0, 0, 0);
    __builtin_amdgcn_s_setprio(0);
  }
  #pragma unroll
  for (int n=0;n<3;++n)
    #pragma unroll
    for (int j=0;j<4;++j)
      obuf[((size_t)b*N_ + q0+row4+j)*D_ + h*HD_ + wc*48 + n*16 + r] = (bf16)oa[n][j];

  // T = K1 Q2^T over col-half (T[q][k] = S2[k][q]); reuse s accs
  #pragma unroll
  for (int n=0;n<18;++n) s[n] = (f32x4){0.f,0.f,0.f,0.f};
  bf16x8 ak[3];
  const bf16* k1row = K1 + ((size_t)(b*H_+h)*N_ + q0 + r)*HD_;
  #pragma unroll
  for (int kk=0;kk<3;++kk) ak[kk] = *(const bf16x8*)(k1row + kk*32 + g*8);
  const bf16* q2b = Q2 + ((size_t)(b*H_+h)*N_ + c0 + r)*HD_ + g*8;
  #pragma unroll
  for (int n=0;n<18;++n) {
    const bf16* qr2 = q2b + (size_t)(n*16)*HD_;
    bf16x8 b0 = *(const bf16x8*)(qr2);
    bf16x8 b1 = *(const bf16x8*)(qr2 + 32);
    bf16x8 b2 = *(const bf16x8*)(qr2 + 64);
    __builtin_amdgcn_s_setprio(1);
    s[n] = __builtin_amdgcn_mfma_f32_16x16x32_bf16(ak[0], b0, s[n], 0, 0, 0);
    s[n] = __builtin_amdgcn_mfma_f32_16x16x32_bf16(ak[1], b1, s[n], 0, 0, 0);
    s[n] = __builtin_amdgcn_mfma_f32_16x16x32_bf16(ak[2], b2, s[n], 0, 0, 0);
    __builtin_amdgcn_s_setprio(0);
  }

  const float* mb = mrow + (size_t)bh*N_;
  const float* rb = rrow + (size_t)bh*N_;
  float* aout = attn_out + (size_t)bh*N_*N_;
  #pragma unroll
  for (int n=0;n<18;++n) {
    const int kc = c0 + n*16 + r;
    const float m2v = mb[kc];
    const float rv  = rb[kc];
    #pragma unroll
    for (int j=0;j<4;++j) {
      const int row = row4 + j;
      float p1 = (float)(*(const bf16*)(pw + ((kc>>3)<<8) + (row<<4) + ((kc&7)<<1)));
      float a2t = __expf((s[n][j] - m2v) * SCALE_F) * rv;
      nt_f32(aout + (size_t)(q0 + row)*N_ + kc, 0.5f*(p1 + a2t));   // final output: nt
    }
  }
}

// ---------------- LayerNorm over 2R rows ----------------
// MODE 0: xres = f32 (x1/x2 per half), y = bf16 -> out bf16 (intermediate: cached)
// MODE 1: xres = bf16, y = bf16 -> out f32 (d_out: nt)
template<int MODE>
__global__ __launch_bounds__(256) void ln_k(
    const float* __restrict__ xf1, const float* __restrict__ xf2,
    const bf16* __restrict__ xb, const bf16* __restrict__ y,
    const float* __restrict__ gamma, const float* __restrict__ beta,
    bf16* __restrict__ out16, float* __restrict__ out32)
{
  const int w = threadIdx.x>>6, lane = threadIdx.x&63;
  const size_t row = (size_t)blockIdx.x*4 + w;
  float v[12]; float s = 0.f, s2 = 0.f;
  const bf16* yr = y + row*D_;
  #pragma unroll
  for (int i=0;i<3;++i) {
    int c = i*256 + lane*4;
    bf16x4 bb = *(const bf16x4*)(yr + c);
    float xr4[4];
    if (MODE == 0) {
      const float* xr = (row < R_) ? (xf1 + row*D_) : (xf2 + (row-R_)*D_);
      f32x4 a = *(const f32x4*)(xr + c);
      #pragma unroll
      for (int q=0;q<4;++q) xr4[q] = a[q];
    } else {
      bf16x4 a = *(const bf16x4*)(xb + row*D_ + c);
      #pragma unroll
      for (int q=0;q<4;++q) xr4[q] = (float)a[q];
    }
    #pragma unroll
    for (int q=0;q<4;++q) {
      float tq = xr4[q] + (float)bb[q];
      v[i*4+q] = tq; s += tq; s2 += tq*tq;
    }
  }
  #pragma unroll
  for (int d=1; d<64; d<<=1) { s += __shfl_xor(s, d); s2 += __shfl_xor(s2, d); }
  const float mean = s*(1.f/D_);
  const float var  = s2*(1.f/D_) - mean*mean;
  const float rstd = rsqrtf(var + 1e-5f);
  #pragma unroll
  for (int i=0;i<3;++i) {
    int c = i*256 + lane*4;
    f32x4 gm = *(const f32x4*)(gamma + c);
    f32x4 bt = *(const f32x4*)(beta  + c);
    float o[4];
    #pragma unroll
    for (int q=0;q<4;++q) o[q] = (v[i*4+q]-mean)*rstd*gm[q] + bt[q];
    if (MODE == 0) {
      union { bf16 h[4]; unsigned long long q64; } u;
      u.h[0]=(bf16)o[0]; u.h[1]=(bf16)o[1]; u.h[2]=(bf16)o[2]; u.h[3]=(bf16)o[3];
      *(unsigned long long*)(out16 + row*D_ + c) = u.q64;   // cached intermediate
    } else {
      f32x4 ov = {o[0], o[1], o[2], o[3]};
      __builtin_nontemporal_store(ov, (f32x4*)(out32 + row*D_ + c));  // d_out: nt
    }
  }
}

// ---------------- host ----------------
extern "C" void kernel_launch(void* const* d_in, const int* in_sizes, int n_in,
                              void* d_out, int out_size, void* d_ws, size_t ws_size,
                              hipStream_t stream)
{
  const float* x1  = (const float*)d_in[0];
  const float* x2  = (const float*)d_in[1];
  const float* Wq  = (const float*)d_in[2];  const float* bq  = (const float*)d_in[3];
  const float* Wk  = (const float*)d_in[4];  const float* bk  = (const float*)d_in[5];
  const float* Wv  = (const float*)d_in[6];  const float* bv  = (const float*)d_in[7];
  const float* Wo  = (const float*)d_in[8];  const float* bo  = (const float*)d_in[9];
  const float* g1  = (const float*)d_in[10]; const float* be1 = (const float*)d_in[11];
  const float* g2  = (const float*)d_in[12]; const float* be2 = (const float*)d_in[13];
  const float* W1  = (const float*)d_in[14]; const float* bf1 = (const float*)d_in[15];
  const float* W2  = (const float*)d_in[16]; const float* bf2 = (const float*)d_in[17];

  float* outLN = (float*)d_out;                     // [2R][D] = out1 | out2
  float* attn  = outLN + (size_t)2*R_*D_;

  char* ws = (char*)d_ws;
  size_t off = 0;
  auto alloc = [&](size_t bytes) -> void* {
    void* p = ws + off;
    off += (bytes + 255) & ~(size_t)255;
    return p;
  };
  const size_t RD2 = (size_t)R_*D_*2;               // one block's bf16 [R][D]
  // span1: xb | Q | K | VT  (4 x 2RD2 = 113.2MB) — aliased by G later
  size_t span1 = off;
  bf16* xb  = (bf16*)alloc(2*RD2);
  bf16* Qb  = (bf16*)alloc(2*RD2);
  bf16* Kb  = (bf16*)alloc(2*RD2);
  bf16* VTb = (bf16*)alloc(2*RD2);
  bf16* G   = (bf16*)(ws + span1);                  // [2R][DF] bf16 = 113.2MB, fits span1
  bf16* wqkvT = (bf16*)alloc((size_t)2304*D_*2);
  float* bqkv = (float*)alloc(2304*4);
  bf16* woT   = (bf16*)alloc((size_t)D_*D_*2);
  bf16* w1T   = (bf16*)alloc((size_t)D_*DF_*2);
  bf16* w2T   = (bf16*)alloc((size_t)DF_*D_*2);
  bf16* obuf  = (bf16*)alloc(2*RD2);
  bf16* oprojB= (bf16*)alloc(2*RD2);
  bf16* h16   = (bf16*)alloc(2*RD2);
  bf16* f16   = (bf16*)alloc(2*RD2);
  float* m2r  = (float*)alloc((size_t)B_*H_*N_*4);
  float* r2r  = (float*)alloc((size_t)B_*H_*N_*4);
  (void)ws_size; (void)in_sizes; (void)n_in; (void)out_size;

  const int n4 = R_*D_/4;
  cast_f32_bf16_k<<<n4/256, 256, 0, stream>>>(x1, xb, n4);
  cast_f32_bf16_k<<<n4/256, 256, 0, stream>>>(x2, xb + (size_t)R_*D_, n4);

  dim3 tb(32,8);
  transpose_cast_k<<<dim3(24,24), tb, 0, stream>>>(Wq, wqkvT,             D_, D_);
  transpose_cast_k<<<dim3(24,24), tb, 0, stream>>>(Wk, wqkvT + 768*D_,    D_, D_);
  transpose_cast_k<<<dim3(24,24), tb, 0, stream>>>(Wv, wqkvT + 1536*D_,   D_, D_);
  transpose_cast_k<<<dim3(24,24), tb, 0, stream>>>(Wo, woT, D_, D_);
  transpose_cast_k<<<dim3(96,24), tb, 0, stream>>>(W1, w1T, D_, DF_);   // -> [3072][768]
  transpose_cast_k<<<dim3(24,96), tb, 0, stream>>>(W2, w2T, DF_, D_);   // -> [768][3072]
  concat_bias_k<<<9, 256, 0, stream>>>(bq, bk, bv, bqkv);

  // fused QKV for BOTH inputs: M=2R=18432, N=2304, K=768 -> grid 72x9=648
  gemm256_k<4,1><<<648, 512, 0, stream>>>(xb, wqkvT, bqkv, Qb, Kb, VTb, 2304, 768, 9);

  // attention (per-s pointers into combined buffers)
  const size_t SD = (size_t)R_*D_;
  attn_stats_k<<<2304, 256, 0, stream>>>(Qb + SD, Kb, VTb, obuf + SD, m2r, r2r);
  attn_map_k  <<<2304, 256, 0, stream>>>(Qb, Kb + SD, VTb + SD, Kb, Qb + SD, m2r, r2r, attn, obuf);

  // combined tails: M=2R for all
  gemm256_k<0,1><<<216, 512, 0, stream>>>(obuf, woT, bo, oprojB, nullptr, nullptr, 768, 768, 3);
  ln_k<0><<<2*R_/4, 256, 0, stream>>>(x1, x2, nullptr, oprojB, g1, be1, h16, nullptr);
  gemm256_k<3,1><<<864, 512, 0, stream>>>(h16, w1T, bf1, G, nullptr, nullptr, 3072, 768, 12);
  gemm256_k<0,0><<<216, 512, 0, stream>>>(G, w2T, bf2, f16, nullptr, nullptr, 768, 3072, 3);
  ln_k<1><<<2*R_/4, 256, 0, stream>>>(nullptr, nullptr, h16, f16, g2, be2, nullptr, outLN);
}